// Round 1
// baseline (11696.829 us; speedup 1.0000x reference)
//
#include <hip/hip_runtime.h>
#include <cstddef>

#define TSEQ 1024
#define CDIM 1024
#define NHEAD 16
#define HSZ 64
#define NLAYER 6
#define VDIM 32000
#define BB 2
#define NROWS (BB * TSEQ)   // 2048

// ---------------------------------------------------------------------------
// Embedding: x[b,t,:] = tok_emb[idx[b,t],:] + pos_emb[t,:]
// ---------------------------------------------------------------------------
__global__ __launch_bounds__(256) void embed_kernel(const int* __restrict__ idx,
    const float* __restrict__ tok, const float* __restrict__ pos,
    float* __restrict__ x) {
  int row = blockIdx.x;            // b*T + t
  int t = row & (TSEQ - 1);
  int c = threadIdx.x * 4;
  int token = idx[row];
  float4 a = *(const float4*)&tok[(size_t)token * CDIM + c];
  float4 p = *(const float4*)&pos[(size_t)t * CDIM + c];
  float4 o;
  o.x = a.x + p.x; o.y = a.y + p.y; o.z = a.z + p.z; o.w = a.w + p.w;
  *(float4*)&x[(size_t)row * CDIM + c] = o;
}

// ---------------------------------------------------------------------------
// LayerNorm over C=1024, one block (256 thr) per row
// ---------------------------------------------------------------------------
__global__ __launch_bounds__(256) void ln_kernel(const float* __restrict__ x,
    float* __restrict__ y, const float* __restrict__ sc,
    const float* __restrict__ bi) {
  int row = blockIdx.x;
  int tid = threadIdx.x;
  const float* xr = x + (size_t)row * CDIM;
  float4 xv = *(const float4*)&xr[tid * 4];
  float sum = xv.x + xv.y + xv.z + xv.w;
  float sq  = xv.x*xv.x + xv.y*xv.y + xv.z*xv.z + xv.w*xv.w;
  #pragma unroll
  for (int off = 32; off > 0; off >>= 1) {
    sum += __shfl_down(sum, off);
    sq  += __shfl_down(sq, off);
  }
  __shared__ float wsum[4], wsq[4], stats[2];
  int wid = tid >> 6, lane = tid & 63;
  if (lane == 0) { wsum[wid] = sum; wsq[wid] = sq; }
  __syncthreads();
  if (tid == 0) {
    float S = 0.f, Q = 0.f;
    #pragma unroll
    for (int i = 0; i < 4; ++i) { S += wsum[i]; Q += wsq[i]; }
    float mu = S * (1.0f / CDIM);
    float var = Q * (1.0f / CDIM) - mu * mu;
    stats[0] = mu;
    stats[1] = 1.0f / sqrtf(var + 1e-5f);
  }
  __syncthreads();
  float mu = stats[0], r = stats[1];
  float4 sv = *(const float4*)&sc[tid * 4];
  float4 bv = *(const float4*)&bi[tid * 4];
  float4 ov;
  ov.x = (xv.x - mu) * r * sv.x + bv.x;
  ov.y = (xv.y - mu) * r * sv.y + bv.y;
  ov.z = (xv.z - mu) * r * sv.z + bv.z;
  ov.w = (xv.w - mu) * r * sv.w + bv.w;
  *(float4*)&y[(size_t)row * CDIM + tid * 4] = ov;
}

// ---------------------------------------------------------------------------
// Transpose one layer's (H,C,HS) weight into interleaved (C, 3072) slot.
// dst is pre-offset by which*1024; row stride 3072.
// ---------------------------------------------------------------------------
__global__ __launch_bounds__(256) void transpose_qkv_kernel(
    const float* __restrict__ w, float* __restrict__ dst) {
  int gid = blockIdx.x * 256 + threadIdx.x;  // over C*C
  int c = gid >> 10;
  int n = gid & (CDIM - 1);
  int h = n >> 6, d = n & (HSZ - 1);
  dst[(size_t)c * 3072 + n] = w[((size_t)h * CDIM + c) * HSZ + d];
}

// ---------------------------------------------------------------------------
// Tiled fp32 GEMM: C(M,N) = A(M,K) @ B(K,N)  [+bias][+relu][+residual]
// Tile: (64*RH) x (64*CH), BK=16, 256 threads, (4*RH)x(4*CH) per thread.
// EPI: 0 none, 1 +bias, 2 +bias+relu, 3 +bias+residual
// All of M,N divisible by tile; K divisible by 16 (asserted by call sites).
// ---------------------------------------------------------------------------
template <int RH, int CH, int EPI>
__global__ __launch_bounds__(256) void gemm_kernel(
    const float* __restrict__ A, const float* __restrict__ Bm,
    float* __restrict__ Cm, const float* __restrict__ bias,
    const float* __restrict__ resid, int M, int N, int K) {
  constexpr int BMt = 64 * RH;
  constexpr int BNt = 64 * CH;
  __shared__ float As[16][BMt + 4];   // +4 pad: staging writes 2-way (free)
  __shared__ float Bs[16][BNt];
  const int tid = threadIdx.x;
  const int bm = blockIdx.y * BMt;
  const int bn = blockIdx.x * BNt;
  const int tr = (tid >> 4) * 4;      // 0..60
  const int tc = (tid & 15) * 4;      // 0..60
  float acc[RH][CH][4][4] = {};
  for (int k0 = 0; k0 < K; k0 += 16) {
    // stage A (BMt x 16), transposed into As[k][m]
    #pragma unroll
    for (int f = tid; f < BMt * 4; f += 256) {
      int row = f >> 2;
      int kq = (f & 3) << 2;
      float4 av = *(const float4*)&A[(size_t)(bm + row) * K + k0 + kq];
      As[kq + 0][row] = av.x;
      As[kq + 1][row] = av.y;
      As[kq + 2][row] = av.z;
      As[kq + 3][row] = av.w;
    }
    // stage B (16 x BNt) row-major
    #pragma unroll
    for (int f = tid; f < BNt * 4; f += 256) {
      int row = f / (BNt / 4);
      int col = (f % (BNt / 4)) * 4;
      *(float4*)&Bs[row][col] =
          *(const float4*)&Bm[(size_t)(k0 + row) * N + bn + col];
    }
    __syncthreads();
    #pragma unroll
    for (int kk = 0; kk < 16; ++kk) {
      float a[RH * 4], b[CH * 4];
      #pragma unroll
      for (int r = 0; r < RH; ++r)
        *(float4*)&a[r * 4] = *(const float4*)&As[kk][tr + r * 64];
      #pragma unroll
      for (int c = 0; c < CH; ++c)
        *(float4*)&b[c * 4] = *(const float4*)&Bs[kk][tc + c * 64];
      #pragma unroll
      for (int r = 0; r < RH; ++r)
        #pragma unroll
        for (int i = 0; i < 4; ++i)
          #pragma unroll
          for (int c = 0; c < CH; ++c)
            #pragma unroll
            for (int j = 0; j < 4; ++j)
              acc[r][c][i][j] += a[r * 4 + i] * b[c * 4 + j];
    }
    __syncthreads();
  }
  // epilogue
  #pragma unroll
  for (int r = 0; r < RH; ++r)
    #pragma unroll
    for (int i = 0; i < 4; ++i) {
      int row = bm + tr + r * 64 + i;
      #pragma unroll
      for (int c = 0; c < CH; ++c) {
        int col = bn + tc + c * 64;
        float4 v = *(float4*)&acc[r][c][i][0];
        if (EPI >= 1) {
          float4 bb = *(const float4*)&bias[col];
          v.x += bb.x; v.y += bb.y; v.z += bb.z; v.w += bb.w;
        }
        if (EPI == 2) {
          v.x = fmaxf(v.x, 0.f); v.y = fmaxf(v.y, 0.f);
          v.z = fmaxf(v.z, 0.f); v.w = fmaxf(v.w, 0.f);
        }
        if (EPI == 3) {
          float4 rr = *(const float4*)&resid[(size_t)row * N + col];
          v.x += rr.x; v.y += rr.y; v.z += rr.z; v.w += rr.w;
        }
        *(float4*)&Cm[(size_t)row * N + col] = v;
      }
    }
}

// ---------------------------------------------------------------------------
// Flash-style causal attention. qkv: (B*T, 3072) rows = [q|k|v], each head 64.
// Block = 256 thr handles 64 query rows of one (b,h). 4 lanes per query row,
// each owning a 16-wide d-slice. K/V tiles (64x64) staged in LDS.
// out: (B*T, 1024) concat-head layout.
// ---------------------------------------------------------------------------
__global__ __launch_bounds__(256) void attn_kernel(
    const float* __restrict__ qkv, float* __restrict__ out) {
  __shared__ float Ks[64][64];
  __shared__ float Vs[64][64];
  const int qb = blockIdx.x, h = blockIdx.y, b = blockIdx.z;
  const int tid = threadIdx.x;
  const int qi = tid >> 2;           // 0..63 query within tile
  const int ds = (tid & 3) * 16;     // d-slice base
  const int tq = qb * 64 + qi;
  const size_t rowQ = (size_t)(b * TSEQ + tq) * 3072 + h * HSZ;
  float qreg[16];
  #pragma unroll
  for (int j = 0; j < 4; ++j)
    *(float4*)&qreg[j * 4] = *(const float4*)&qkv[rowQ + ds + j * 4];
  float oreg[16] = {};
  float m = -1e30f, l = 0.f;
  for (int kt = 0; kt <= qb; ++kt) {
    __syncthreads();
    #pragma unroll
    for (int i = 0; i < 4; ++i) {
      int f = tid + i * 256;          // 1024 float4 slots
      int r = f >> 4;
      int col = (f & 15) * 4;
      size_t g = (size_t)(b * TSEQ + kt * 64 + r) * 3072 + h * HSZ + col;
      *(float4*)&Ks[r][col] = *(const float4*)&qkv[1024 + g];
      *(float4*)&Vs[r][col] = *(const float4*)&qkv[2048 + g];
    }
    __syncthreads();
    const int smax = (kt == qb) ? (qi + 1) : 64;
    for (int s = 0; s < smax; ++s) {
      float p = 0.f;
      #pragma unroll
      for (int j = 0; j < 16; ++j) p += qreg[j] * Ks[s][ds + j];
      p += __shfl_xor(p, 1);
      p += __shfl_xor(p, 2);
      p *= 0.125f;                    // 1/sqrt(64)
      float nm = fmaxf(m, p);
      float w = __expf(p - nm);
      float corr = __expf(m - nm);
      l = l * corr + w;
      #pragma unroll
      for (int j = 0; j < 16; ++j)
        oreg[j] = oreg[j] * corr + w * Vs[s][ds + j];
      m = nm;
    }
  }
  float inv = 1.f / l;
  const size_t rowO = (size_t)(b * TSEQ + tq) * CDIM + h * HSZ;
  #pragma unroll
  for (int j = 0; j < 4; ++j) {
    float4 t4;
    t4.x = oreg[j * 4 + 0] * inv;
    t4.y = oreg[j * 4 + 1] * inv;
    t4.z = oreg[j * 4 + 2] * inv;
    t4.w = oreg[j * 4 + 3] * inv;
    *(float4*)&out[rowO + ds + j * 4] = t4;
  }
}

// ---------------------------------------------------------------------------
extern "C" void kernel_launch(void* const* d_in, const int* in_sizes, int n_in,
                              void* d_out, int out_size, void* d_ws,
                              size_t ws_size, hipStream_t stream) {
  (void)in_sizes; (void)n_in; (void)out_size; (void)ws_size;
  const int*   idx     = (const int*)  d_in[0];
  const float* tok_emb = (const float*)d_in[1];
  const float* pos_emb = (const float*)d_in[2];
  const float* Wq      = (const float*)d_in[3];
  const float* Wk      = (const float*)d_in[4];
  const float* Wv      = (const float*)d_in[5];
  const float* Wo      = (const float*)d_in[6];
  const float* bo      = (const float*)d_in[7];
  const float* ln1_s   = (const float*)d_in[8];
  const float* ln1_b   = (const float*)d_in[9];
  const float* ln2_s   = (const float*)d_in[10];
  const float* ln2_b   = (const float*)d_in[11];
  const float* W1      = (const float*)d_in[12];
  const float* b1      = (const float*)d_in[13];
  const float* W2      = (const float*)d_in[14];
  const float* b2      = (const float*)d_in[15];
  const float* lnf_s   = (const float*)d_in[16];
  const float* lnf_b   = (const float*)d_in[17];
  const float* W_lm    = (const float*)d_in[18];
  const float* b_lm    = (const float*)d_in[19];
  float* out = (float*)d_out;

  // workspace layout (floats); total 11.5*SZ = 24.1M floats = 96.5 MB
  const size_t SZ = (size_t)NROWS * CDIM;  // 2,097,152
  float* ws   = (float*)d_ws;
  float* x    = ws;             // residual stream       (SZ)
  float* hbuf = ws + SZ;        // LN output             (SZ)
  float* qkv  = ws + 2 * SZ;    // fused qkv             (3*SZ)
  float* att  = ws + 5 * SZ;    // attention out         (SZ)
  float* mid  = ws + 6 * SZ;    // MLP hidden            (4*SZ)
  float* wt3  = ws + 10 * SZ;   // transposed qkv weights (1.5*SZ)

  embed_kernel<<<NROWS, 256, 0, stream>>>(idx, tok_emb, pos_emb, x);

  for (int l = 0; l < NLAYER; ++l) {
    ln_kernel<<<NROWS, 256, 0, stream>>>(x, hbuf, ln1_s + l * CDIM,
                                         ln1_b + l * CDIM);
    const size_t wqkv_off = (size_t)l * NHEAD * CDIM * HSZ;
    transpose_qkv_kernel<<<CDIM * CDIM / 256, 256, 0, stream>>>(
        Wq + wqkv_off, wt3);
    transpose_qkv_kernel<<<CDIM * CDIM / 256, 256, 0, stream>>>(
        Wk + wqkv_off, wt3 + 1024);
    transpose_qkv_kernel<<<CDIM * CDIM / 256, 256, 0, stream>>>(
        Wv + wqkv_off, wt3 + 2048);
    // fused QKV GEMM: (2048x1024) @ (1024x3072)
    gemm_kernel<2, 2, 0><<<dim3(3072 / 128, NROWS / 128), 256, 0, stream>>>(
        hbuf, wt3, qkv, nullptr, nullptr, NROWS, 3072, CDIM);
    attn_kernel<<<dim3(TSEQ / 64, NHEAD, BB), 256, 0, stream>>>(qkv, att);
    // x = x + att @ Wo + bo   (128x64 tiles -> 256 blocks)
    gemm_kernel<2, 1, 3><<<dim3(CDIM / 64, NROWS / 128), 256, 0, stream>>>(
        att, Wo + (size_t)l * CDIM * CDIM, x, bo + l * CDIM, x,
        NROWS, CDIM, CDIM);
    ln_kernel<<<NROWS, 256, 0, stream>>>(x, hbuf, ln2_s + l * CDIM,
                                         ln2_b + l * CDIM);
    // mid = relu(h @ W1 + b1)
    gemm_kernel<2, 2, 2><<<dim3(4096 / 128, NROWS / 128), 256, 0, stream>>>(
        hbuf, W1 + (size_t)l * CDIM * 4096, mid, b1 + l * 4096, nullptr,
        NROWS, 4096, CDIM);
    // x = x + mid @ W2 + b2
    gemm_kernel<2, 1, 3><<<dim3(CDIM / 64, NROWS / 128), 256, 0, stream>>>(
        mid, W2 + (size_t)l * 4096 * CDIM, x, b2 + l * CDIM, x,
        NROWS, CDIM, 4096);
  }

  ln_kernel<<<NROWS, 256, 0, stream>>>(x, hbuf, lnf_s, lnf_b);
  // logits = h @ W_lm + b_lm   : (2048x1024)@(1024x32000)
  gemm_kernel<2, 2, 1><<<dim3(VDIM / 128, NROWS / 128), 256, 0, stream>>>(
      hbuf, W_lm, out, b_lm, nullptr, NROWS, VDIM, CDIM);
}

// Round 3
// 4538.955 us; speedup vs baseline: 2.5770x; 2.5770x over previous
//
#include <hip/hip_runtime.h>
#include <cstddef>
#include <cstdint>

#define TSEQ 1024
#define CDIM 1024
#define NHEAD 16
#define HSZ 64
#define NLAYER 6
#define VDIM 32000
#define BB 2
#define NROWS (BB * TSEQ)   // 2048

typedef unsigned short u16;
typedef __attribute__((ext_vector_type(8))) short short8;   // 8 bf16 (4 VGPR)
typedef __attribute__((ext_vector_type(4))) float f32x4;    // MFMA acc
typedef __attribute__((ext_vector_type(4))) u16 u16x4;

// ---------------------------------------------------------------------------
// helpers: RNE fp32 -> bf16, and 2-term split (hi + lo ~= 16 mantissa bits)
// ---------------------------------------------------------------------------
__device__ inline unsigned bf16rne(float x) {
  unsigned u = __float_as_uint(x);
  return (u + 0x7FFFu + ((u >> 16) & 1u)) >> 16;
}
__device__ inline void split2(float x, u16& h, u16& l) {
  unsigned hb = bf16rne(x);
  h = (u16)hb;
  float r = x - __uint_as_float(hb << 16);
  l = (u16)bf16rne(r);
}

// async global->LDS, 16B per lane; LDS dest = uniform base + lane*16
__device__ inline void gload_lds16(const void* g, void* l) {
  __builtin_amdgcn_global_load_lds(
      (const __attribute__((address_space(1))) unsigned int*)g,
      (__attribute__((address_space(3))) unsigned int*)l, 16, 0, 0);
}

// ---------------------------------------------------------------------------
// Embedding: x[b,t,:] = tok_emb[idx[b,t],:] + pos_emb[t,:]   (fp32 residual)
// ---------------------------------------------------------------------------
__global__ __launch_bounds__(256) void embed_kernel(const int* __restrict__ idx,
    const float* __restrict__ tok, const float* __restrict__ pos,
    float* __restrict__ x) {
  int row = blockIdx.x;
  int t = row & (TSEQ - 1);
  int c = threadIdx.x * 4;
  int token = idx[row];
  float4 a = *(const float4*)&tok[(size_t)token * CDIM + c];
  float4 p = *(const float4*)&pos[(size_t)t * CDIM + c];
  float4 o;
  o.x = a.x + p.x; o.y = a.y + p.y; o.z = a.z + p.z; o.w = a.w + p.w;
  *(float4*)&x[(size_t)row * CDIM + c] = o;
}

// ---------------------------------------------------------------------------
// LayerNorm over C=1024; emits split bf16 planes (hi, lo)
// ---------------------------------------------------------------------------
__global__ __launch_bounds__(256) void ln_kernel(const float* __restrict__ x,
    u16* __restrict__ yh, u16* __restrict__ yl,
    const float* __restrict__ sc, const float* __restrict__ bi) {
  int row = blockIdx.x;
  int tid = threadIdx.x;
  const float* xr = x + (size_t)row * CDIM;
  float4 xv = *(const float4*)&xr[tid * 4];
  float sum = xv.x + xv.y + xv.z + xv.w;
  float sq  = xv.x*xv.x + xv.y*xv.y + xv.z*xv.z + xv.w*xv.w;
  #pragma unroll
  for (int off = 32; off > 0; off >>= 1) {
    sum += __shfl_down(sum, off);
    sq  += __shfl_down(sq, off);
  }
  __shared__ float wsum[4], wsq[4], stats[2];
  int wid = tid >> 6, lane = tid & 63;
  if (lane == 0) { wsum[wid] = sum; wsq[wid] = sq; }
  __syncthreads();
  if (tid == 0) {
    float S = 0.f, Q = 0.f;
    #pragma unroll
    for (int i = 0; i < 4; ++i) { S += wsum[i]; Q += wsq[i]; }
    float mu = S * (1.0f / CDIM);
    float var = Q * (1.0f / CDIM) - mu * mu;
    stats[0] = mu;
    stats[1] = 1.0f / sqrtf(var + 1e-5f);
  }
  __syncthreads();
  float mu = stats[0], r = stats[1];
  float4 sv = *(const float4*)&sc[tid * 4];
  float4 bv = *(const float4*)&bi[tid * 4];
  float o0 = (xv.x - mu) * r * sv.x + bv.x;
  float o1 = (xv.y - mu) * r * sv.y + bv.y;
  float o2 = (xv.z - mu) * r * sv.z + bv.z;
  float o3 = (xv.w - mu) * r * sv.w + bv.w;
  u16x4 hv, lv;
  u16 hh, ll;
  split2(o0, hh, ll); hv[0] = hh; lv[0] = ll;
  split2(o1, hh, ll); hv[1] = hh; lv[1] = ll;
  split2(o2, hh, ll); hv[2] = hh; lv[2] = ll;
  split2(o3, hh, ll); hv[3] = hh; lv[3] = ll;
  size_t o = (size_t)row * CDIM + tid * 4;
  *(u16x4*)&yh[o] = hv;
  *(u16x4*)&yl[o] = lv;
}

// ---------------------------------------------------------------------------
// Weight transpose + split-convert: src (Ksrc x Nsrc tile) fp32, row stride
// ldsrc, col offset col0 -> dst planes Bt[n][k] (row stride ldd).
// grid: (ncols/32, Ksrc/32, nz); per-z strides zsrc/zdst (QKV heads).
// ---------------------------------------------------------------------------
__global__ __launch_bounds__(256) void wcvt_kernel(const float* __restrict__ src,
    int ldsrc, int col0, u16* __restrict__ dh, u16* __restrict__ dl, int ldd,
    size_t zsrc, size_t zdst) {
  src += blockIdx.z * zsrc;
  dh  += blockIdx.z * zdst;
  dl  += blockIdx.z * zdst;
  __shared__ float t[32][33];
  int n0 = blockIdx.x * 32, k0 = blockIdx.y * 32;
  int tid = threadIdx.x;
  int r = tid >> 3;            // 0..31
  int c4 = (tid & 7) * 4;      // 0..28
  float4 v = *(const float4*)&src[(size_t)(k0 + r) * ldsrc + col0 + n0 + c4];
  t[c4 + 0][r] = v.x;  // t[n_local][k_local]
  t[c4 + 1][r] = v.y;
  t[c4 + 2][r] = v.z;
  t[c4 + 3][r] = v.w;
  __syncthreads();
  u16x4 hv, lv;
  u16 hh, ll;
  #pragma unroll
  for (int i = 0; i < 4; ++i) {
    split2(t[r][c4 + i], hh, ll);
    hv[i] = hh; lv[i] = ll;
  }
  size_t o = (size_t)(n0 + r) * ldd + k0 + c4;
  *(u16x4*)&dh[o] = hv;
  *(u16x4*)&dl[o] = lv;
}

// ---------------------------------------------------------------------------
// Split-bf16 MFMA GEMM: C(M,N) = A(M,K) @ B(N,K)^T with A,B as (hi,lo) bf16
// plane pairs; acc = Ah*Bh + Ah*Bl + Al*Bh (fp32 accumulate) ~= fp32 GEMM.
// m97 structure: BK=32, 4 waves, global_load_lds(16B), 16x16x32 MFMA.
// EPI: 0 plain fp32; 1 +bias fp32; 2 +bias,relu -> split planes; 3 +bias+resid fp32
// ---------------------------------------------------------------------------
template <int BM, int BN, int WM, int WN, int EPI>
__global__ __launch_bounds__(256) void mgemm(
    const u16* __restrict__ Ah, const u16* __restrict__ Al,
    const u16* __restrict__ Bh, const u16* __restrict__ Bl,
    float* __restrict__ Cf, u16* __restrict__ Ch, u16* __restrict__ Cl,
    const float* __restrict__ bias, const float* __restrict__ resid,
    int M, int N, int K, int ldC) {
  constexpr int WR = BM / WM;
  constexpr int WC = BN / WN;
  static_assert(WR * WC == 4, "4 waves");
  constexpr int FM = WM / 16, FN = WN / 16;
  __shared__ u16 As[2][BM * 32];   // [plane][row*32 + k]
  __shared__ u16 Bs[2][BN * 32];
  const int tid = threadIdx.x;
  const int wid = tid >> 6, lane = tid & 63;
  const int wr = wid / WC, wc = wid % WC;
  const int bm = blockIdx.y * BM, bn = blockIdx.x * BN;
  const int arow = lane & 15;
  const int kgrp = lane >> 4;          // 0..3
  const int strow = lane >> 2;         // 0..15 staging row within 16-row chunk
  const int stk = (lane & 3) * 8;      // staging k element
  f32x4 acc[FM][FN] = {};

  for (int k0 = 0; k0 < K; k0 += 32) {
    // ---- stage A/B hi+lo tiles via async global->LDS ----
    #pragma unroll
    for (int p = 0; p < 2; ++p) {
      const u16* Ap = p ? Al : Ah;
      #pragma unroll
      for (int i = 0; i < BM / 64; ++i) {
        int r0 = (wid + 4 * i) * 16;
        gload_lds16(Ap + (size_t)(bm + r0 + strow) * K + k0 + stk,
                    &As[p][r0 * 32]);
      }
      const u16* Bp = p ? Bl : Bh;
      #pragma unroll
      for (int i = 0; i < BN / 64; ++i) {
        int r0 = (wid + 4 * i) * 16;
        gload_lds16(Bp + (size_t)(bn + r0 + strow) * K + k0 + stk,
                    &Bs[p][r0 * 32]);
      }
    }
    __syncthreads();
    // ---- fragments + 3-term MFMA ----
    short8 ah[FM], al[FM], bh[FN], bl[FN];
    #pragma unroll
    for (int mi = 0; mi < FM; ++mi) {
      int off = (wr * WM + mi * 16 + arow) * 32 + kgrp * 8;
      ah[mi] = *(const short8*)&As[0][off];
      al[mi] = *(const short8*)&As[1][off];
    }
    #pragma unroll
    for (int ni = 0; ni < FN; ++ni) {
      int off = (wc * WN + ni * 16 + arow) * 32 + kgrp * 8;
      bh[ni] = *(const short8*)&Bs[0][off];
      bl[ni] = *(const short8*)&Bs[1][off];
    }
    #pragma unroll
    for (int mi = 0; mi < FM; ++mi)
      #pragma unroll
      for (int ni = 0; ni < FN; ++ni) {
        acc[mi][ni] = __builtin_amdgcn_mfma_f32_16x16x32_bf16(
            ah[mi], bh[ni], acc[mi][ni], 0, 0, 0);
        acc[mi][ni] = __builtin_amdgcn_mfma_f32_16x16x32_bf16(
            ah[mi], bl[ni], acc[mi][ni], 0, 0, 0);
        acc[mi][ni] = __builtin_amdgcn_mfma_f32_16x16x32_bf16(
            al[mi], bh[ni], acc[mi][ni], 0, 0, 0);
      }
    __syncthreads();
  }
  // ---- epilogue; C/D layout: col = lane&15, row = (lane>>4)*4 + j ----
  #pragma unroll
  for (int mi = 0; mi < FM; ++mi)
    #pragma unroll
    for (int ni = 0; ni < FN; ++ni) {
      int col = bn + wc * WN + ni * 16 + (lane & 15);
      float bv = (EPI >= 1) ? bias[col] : 0.f;
      #pragma unroll
      for (int j = 0; j < 4; ++j) {
        int row = bm + wr * WM + mi * 16 + (lane >> 4) * 4 + j;
        float v = acc[mi][ni][j] + bv;
        size_t o = (size_t)row * ldC + col;
        if (EPI == 2) {
          v = fmaxf(v, 0.f);
          u16 hh, ll;
          split2(v, hh, ll);
          Ch[o] = hh;
          Cl[o] = ll;
        } else if (EPI == 3) {
          Cf[o] = v + resid[o];
        } else {
          Cf[o] = v;
        }
      }
    }
}

// ---------------------------------------------------------------------------
// Flash-style causal attention (fp32 math; emits split planes for Wo GEMM).
// qkv rows (B*T, 3072) = [q|k|v]; 256 thr per 64 query rows of one (b,h).
// ---------------------------------------------------------------------------
__global__ __launch_bounds__(256) void attn_kernel(
    const float* __restrict__ qkv, u16* __restrict__ oh, u16* __restrict__ ol) {
  __shared__ float Ks[64][64];
  __shared__ float Vs[64][64];
  const int qb = blockIdx.x, h = blockIdx.y, b = blockIdx.z;
  const int tid = threadIdx.x;
  const int qi = tid >> 2;
  const int ds = (tid & 3) * 16;
  const int tq = qb * 64 + qi;
  const size_t rowQ = (size_t)(b * TSEQ + tq) * 3072 + h * HSZ;
  float qreg[16];
  #pragma unroll
  for (int j = 0; j < 4; ++j)
    *(float4*)&qreg[j * 4] = *(const float4*)&qkv[rowQ + ds + j * 4];
  float oreg[16] = {};
  float m = -1e30f, l = 0.f;
  for (int kt = 0; kt <= qb; ++kt) {
    __syncthreads();
    #pragma unroll
    for (int i = 0; i < 4; ++i) {
      int f = tid + i * 256;
      int r = f >> 4;
      int col = (f & 15) * 4;
      size_t g = (size_t)(b * TSEQ + kt * 64 + r) * 3072 + h * HSZ + col;
      *(float4*)&Ks[r][col] = *(const float4*)&qkv[1024 + g];
      *(float4*)&Vs[r][col] = *(const float4*)&qkv[2048 + g];
    }
    __syncthreads();
    const int smax = (kt == qb) ? (qi + 1) : 64;
    for (int s = 0; s < smax; ++s) {
      float p = 0.f;
      #pragma unroll
      for (int j = 0; j < 16; ++j) p += qreg[j] * Ks[s][ds + j];
      p += __shfl_xor(p, 1);
      p += __shfl_xor(p, 2);
      p *= 0.125f;
      float nm = fmaxf(m, p);
      float w = __expf(p - nm);
      float corr = __expf(m - nm);
      l = l * corr + w;
      #pragma unroll
      for (int j = 0; j < 16; ++j)
        oreg[j] = oreg[j] * corr + w * Vs[s][ds + j];
      m = nm;
    }
  }
  float inv = 1.f / l;
  const size_t rowO = (size_t)(b * TSEQ + tq) * CDIM + h * HSZ + ds;
  #pragma unroll
  for (int j = 0; j < 4; ++j) {
    u16x4 hv, lv;
    #pragma unroll
    for (int q = 0; q < 4; ++q) {
      u16 hh, ll;
      split2(oreg[j * 4 + q] * inv, hh, ll);
      hv[q] = hh; lv[q] = ll;
    }
    *(u16x4*)&oh[rowO + j * 4] = hv;
    *(u16x4*)&ol[rowO + j * 4] = lv;
  }
}

// ---------------------------------------------------------------------------
extern "C" void kernel_launch(void* const* d_in, const int* in_sizes, int n_in,
                              void* d_out, int out_size, void* d_ws,
                              size_t ws_size, hipStream_t stream) {
  (void)in_sizes; (void)n_in; (void)out_size; (void)ws_size;
  const int*   idx     = (const int*)  d_in[0];
  const float* tok_emb = (const float*)d_in[1];
  const float* pos_emb = (const float*)d_in[2];
  const float* Wq      = (const float*)d_in[3];
  const float* Wk      = (const float*)d_in[4];
  const float* Wv      = (const float*)d_in[5];
  const float* Wo      = (const float*)d_in[6];
  const float* bo      = (const float*)d_in[7];
  const float* ln1_s   = (const float*)d_in[8];
  const float* ln1_b   = (const float*)d_in[9];
  const float* ln2_s   = (const float*)d_in[10];
  const float* ln2_b   = (const float*)d_in[11];
  const float* W1      = (const float*)d_in[12];
  const float* b1      = (const float*)d_in[13];
  const float* W2      = (const float*)d_in[14];
  const float* b2      = (const float*)d_in[15];
  const float* lnf_s   = (const float*)d_in[16];
  const float* lnf_b   = (const float*)d_in[17];
  const float* W_lm    = (const float*)d_in[18];
  const float* b_lm    = (const float*)d_in[19];
  float* out = (float*)d_out;

  // workspace map (bytes), total 84,934,656 < 96.5MB proven bound
  char* wsb = (char*)d_ws;
  float* x    = (float*)wsb;                    //  8,388,608 fp32 residual
  u16* h_h    = (u16*)(wsb + 8388608);          //  4,194,304 LN out hi
  u16* h_l    = (u16*)(wsb + 12582912);         //  4,194,304 LN out lo
  u16* att_h  = (u16*)(wsb + 16777216);         //  4,194,304
  u16* att_l  = (u16*)(wsb + 20971520);         //  4,194,304
  char* big   = wsb + 25165824;                 // 33,554,432 shared qkv/mid
  float* qkv  = (float*)big;                    // 25,165,824 (B*T,3072) fp32
  u16* mid_h  = (u16*)big;                      // 16,777,216 (B*T,4096) hi
  u16* mid_l  = (u16*)(big + 16777216);         // 16,777,216 lo
  u16* wb_h   = (u16*)(wsb + 58720256);         // 13,107,200 weight plane hi
  u16* wb_l   = (u16*)(wsb + 71827456);         // 13,107,200 weight plane lo

  embed_kernel<<<NROWS, 256, 0, stream>>>(idx, tok_emb, pos_emb, x);

  for (int l = 0; l < NLAYER; ++l) {
    ln_kernel<<<NROWS, 256, 0, stream>>>(x, h_h, h_l, ln1_s + l * CDIM,
                                         ln1_b + l * CDIM);
    // QKV weights: (H,C,HS) -> Bt[h*64+d][c], 3 tensors into one 3072x1024
    const size_t lq = (size_t)l * NHEAD * CDIM * HSZ;
    wcvt_kernel<<<dim3(2, 32, 16), 256, 0, stream>>>(
        Wq + lq, HSZ, 0, wb_h, wb_l, CDIM, (size_t)CDIM * HSZ, (size_t)HSZ * CDIM);
    wcvt_kernel<<<dim3(2, 32, 16), 256, 0, stream>>>(
        Wk + lq, HSZ, 0, wb_h + 1048576, wb_l + 1048576, CDIM,
        (size_t)CDIM * HSZ, (size_t)HSZ * CDIM);
    wcvt_kernel<<<dim3(2, 32, 16), 256, 0, stream>>>(
        Wv + lq, HSZ, 0, wb_h + 2097152, wb_l + 2097152, CDIM,
        (size_t)CDIM * HSZ, (size_t)HSZ * CDIM);
    mgemm<128, 128, 64, 64, 0><<<dim3(3072 / 128, NROWS / 128), 256, 0, stream>>>(
        h_h, h_l, wb_h, wb_l, qkv, nullptr, nullptr, nullptr, nullptr,
        NROWS, 3072, CDIM, 3072);
    attn_kernel<<<dim3(TSEQ / 64, NHEAD, BB), 256, 0, stream>>>(qkv, att_h, att_l);
    // Wo: x += att @ Wo + bo
    wcvt_kernel<<<dim3(32, 32, 1), 256, 0, stream>>>(
        Wo + (size_t)l * CDIM * CDIM, CDIM, 0, wb_h, wb_l, CDIM, 0, 0);
    mgemm<64, 128, 32, 64, 3><<<dim3(CDIM / 128, NROWS / 64), 256, 0, stream>>>(
        att_h, att_l, wb_h, wb_l, x, nullptr, nullptr, bo + l * CDIM, x,
        NROWS, CDIM, CDIM, CDIM);
    ln_kernel<<<NROWS, 256, 0, stream>>>(x, h_h, h_l, ln2_s + l * CDIM,
                                         ln2_b + l * CDIM);
    // MLP1: mid = relu(h @ W1 + b1) -> planes
    wcvt_kernel<<<dim3(128, 32, 1), 256, 0, stream>>>(
        W1 + (size_t)l * CDIM * 4096, 4096, 0, wb_h, wb_l, CDIM, 0, 0);
    mgemm<128, 128, 64, 64, 2><<<dim3(4096 / 128, NROWS / 128), 256, 0, stream>>>(
        h_h, h_l, wb_h, wb_l, nullptr, mid_h, mid_l, b1 + l * 4096, nullptr,
        NROWS, 4096, CDIM, 4096);
    // MLP2: x += mid @ W2 + b2
    wcvt_kernel<<<dim3(32, 128, 1), 256, 0, stream>>>(
        W2 + (size_t)l * 4096 * CDIM, CDIM, 0, wb_h, wb_l, 4096, 0, 0);
    mgemm<64, 128, 32, 64, 3><<<dim3(CDIM / 128, NROWS / 64), 256, 0, stream>>>(
        mid_h, mid_l, wb_h, wb_l, x, nullptr, nullptr, b2 + l * CDIM, x,
        NROWS, CDIM, 4096, CDIM);
  }

  ln_kernel<<<NROWS, 256, 0, stream>>>(x, h_h, h_l, lnf_s, lnf_b);
  // LM head in 5 chunks of N=6400 to bound workspace
  for (int c = 0; c < 5; ++c) {
    int col0 = c * 6400;
    wcvt_kernel<<<dim3(200, 32, 1), 256, 0, stream>>>(
        W_lm, VDIM, col0, wb_h, wb_l, CDIM, 0, 0);
    mgemm<128, 128, 64, 64, 1><<<dim3(50, NROWS / 128), 256, 0, stream>>>(
        h_h, h_l, wb_h, wb_l, out + col0, nullptr, nullptr, b_lm + col0,
        nullptr, NROWS, 6400, CDIM, VDIM);
  }
}

// Round 8
// 3224.480 us; speedup vs baseline: 3.6275x; 1.4077x over previous
//
#include <hip/hip_runtime.h>
#include <cstddef>
#include <cstdint>

#define TSEQ 1024
#define CDIM 1024
#define NHEAD 16
#define HSZ 64
#define NLAYER 6
#define VDIM 32000
#define BB 2
#define NROWS (BB * TSEQ)   // 2048

typedef unsigned short u16;
typedef __attribute__((ext_vector_type(8))) short short8;   // 8 bf16 (4 VGPR)
typedef __attribute__((ext_vector_type(4))) float f32x4;    // MFMA acc
typedef __attribute__((ext_vector_type(4))) u16 u16x4;

// ---------------------------------------------------------------------------
// helpers: RNE fp32 -> bf16, and 2-term split (hi + lo ~= 16 mantissa bits)
// ---------------------------------------------------------------------------
__device__ inline unsigned bf16rne(float x) {
  unsigned u = __float_as_uint(x);
  return (u + 0x7FFFu + ((u >> 16) & 1u)) >> 16;
}
__device__ inline void split2(float x, u16& h, u16& l) {
  unsigned hb = bf16rne(x);
  h = (u16)hb;
  float r = x - __uint_as_float(hb << 16);
  l = (u16)bf16rne(r);
}

// async global->LDS, 16B per lane; LDS dest = uniform base + lane*16
__device__ inline void gload_lds16(const void* g, void* l) {
  __builtin_amdgcn_global_load_lds(
      (const __attribute__((address_space(1))) unsigned int*)g,
      (__attribute__((address_space(3))) unsigned int*)l, 16, 0, 0);
}

// ---------------------------------------------------------------------------
// Embedding: x[b,t,:] = tok_emb[idx[b,t],:] + pos_emb[t,:]   (fp32 residual)
// ---------------------------------------------------------------------------
__global__ __launch_bounds__(256) void embed_kernel(const int* __restrict__ idx,
    const float* __restrict__ tok, const float* __restrict__ pos,
    float* __restrict__ x) {
  int row = blockIdx.x;
  int t = row & (TSEQ - 1);
  int c = threadIdx.x * 4;
  int token = idx[row];
  float4 a = *(const float4*)&tok[(size_t)token * CDIM + c];
  float4 p = *(const float4*)&pos[(size_t)t * CDIM + c];
  float4 o;
  o.x = a.x + p.x; o.y = a.y + p.y; o.z = a.z + p.z; o.w = a.w + p.w;
  *(float4*)&x[(size_t)row * CDIM + c] = o;
}

// ---------------------------------------------------------------------------
// LayerNorm over C=1024; emits split bf16 planes (hi, lo)
// ---------------------------------------------------------------------------
__global__ __launch_bounds__(256) void ln_kernel(const float* __restrict__ x,
    u16* __restrict__ yh, u16* __restrict__ yl,
    const float* __restrict__ sc, const float* __restrict__ bi) {
  int row = blockIdx.x;
  int tid = threadIdx.x;
  const float* xr = x + (size_t)row * CDIM;
  float4 xv = *(const float4*)&xr[tid * 4];
  float sum = xv.x + xv.y + xv.z + xv.w;
  float sq  = xv.x*xv.x + xv.y*xv.y + xv.z*xv.z + xv.w*xv.w;
  #pragma unroll
  for (int off = 32; off > 0; off >>= 1) {
    sum += __shfl_down(sum, off);
    sq  += __shfl_down(sq, off);
  }
  __shared__ float wsum[4], wsq[4], stats[2];
  int wid = tid >> 6, lane = tid & 63;
  if (lane == 0) { wsum[wid] = sum; wsq[wid] = sq; }
  __syncthreads();
  if (tid == 0) {
    float S = 0.f, Q = 0.f;
    #pragma unroll
    for (int i = 0; i < 4; ++i) { S += wsum[i]; Q += wsq[i]; }
    float mu = S * (1.0f / CDIM);
    float var = Q * (1.0f / CDIM) - mu * mu;
    stats[0] = mu;
    stats[1] = 1.0f / sqrtf(var + 1e-5f);
  }
  __syncthreads();
  float mu = stats[0], r = stats[1];
  float4 sv = *(const float4*)&sc[tid * 4];
  float4 bv = *(const float4*)&bi[tid * 4];
  float o0 = (xv.x - mu) * r * sv.x + bv.x;
  float o1 = (xv.y - mu) * r * sv.y + bv.y;
  float o2 = (xv.z - mu) * r * sv.z + bv.z;
  float o3 = (xv.w - mu) * r * sv.w + bv.w;
  u16x4 hv, lv;
  u16 hh, ll;
  split2(o0, hh, ll); hv[0] = hh; lv[0] = ll;
  split2(o1, hh, ll); hv[1] = hh; lv[1] = ll;
  split2(o2, hh, ll); hv[2] = hh; lv[2] = ll;
  split2(o3, hh, ll); hv[3] = hh; lv[3] = ll;
  size_t o = (size_t)row * CDIM + tid * 4;
  *(u16x4*)&yh[o] = hv;
  *(u16x4*)&yl[o] = lv;
}

// ---------------------------------------------------------------------------
// Weight transpose + split-convert: src (Ksrc x Nsrc tile) fp32 -> Bt[n][k]
// ---------------------------------------------------------------------------
__global__ __launch_bounds__(256) void wcvt_kernel(const float* __restrict__ src,
    int ldsrc, int col0, u16* __restrict__ dh, u16* __restrict__ dl, int ldd,
    size_t zsrc, size_t zdst) {
  src += blockIdx.z * zsrc;
  dh  += blockIdx.z * zdst;
  dl  += blockIdx.z * zdst;
  __shared__ float t[32][33];
  int n0 = blockIdx.x * 32, k0 = blockIdx.y * 32;
  int tid = threadIdx.x;
  int r = tid >> 3;            // 0..31
  int c4 = (tid & 7) * 4;      // 0..28
  float4 v = *(const float4*)&src[(size_t)(k0 + r) * ldsrc + col0 + n0 + c4];
  t[c4 + 0][r] = v.x;
  t[c4 + 1][r] = v.y;
  t[c4 + 2][r] = v.z;
  t[c4 + 3][r] = v.w;
  __syncthreads();
  u16x4 hv, lv;
  u16 hh, ll;
  #pragma unroll
  for (int i = 0; i < 4; ++i) {
    split2(t[r][c4 + i], hh, ll);
    hv[i] = hh; lv[i] = ll;
  }
  size_t o = (size_t)(n0 + r) * ldd + k0 + c4;
  *(u16x4*)&dh[o] = hv;
  *(u16x4*)&dl[o] = lv;
}

// ---------------------------------------------------------------------------
// Split-bf16 MFMA GEMM. EPI: 0 fp32; 1 +bias fp32; 2 +bias,relu->planes;
// 3 +bias+resid fp32; 4 qkv-split (Q,K planes [bh,t,64]; V^T planes [bh,64,t])
// ---------------------------------------------------------------------------
template <int BM, int BN, int WM, int WN, int EPI>
__global__ __launch_bounds__(256) void mgemm(
    const u16* __restrict__ Ah, const u16* __restrict__ Al,
    const u16* __restrict__ Bh, const u16* __restrict__ Bl,
    float* __restrict__ Cf, u16* __restrict__ Ch, u16* __restrict__ Cl,
    u16* __restrict__ Ch2, u16* __restrict__ Cl2,
    u16* __restrict__ Ch3, u16* __restrict__ Cl3,
    const float* __restrict__ bias, const float* __restrict__ resid,
    int M, int N, int K, int ldC) {
  constexpr int WR = BM / WM;
  constexpr int WC = BN / WN;
  static_assert(WR * WC == 4, "4 waves");
  constexpr int FM = WM / 16, FN = WN / 16;
  __shared__ u16 As[2][BM * 32];   // [plane][row*32 + k]
  __shared__ u16 Bs[2][BN * 32];
  const int tid = threadIdx.x;
  const int wid = tid >> 6, lane = tid & 63;
  const int wr = wid / WC, wc = wid % WC;
  const int bm = blockIdx.y * BM, bn = blockIdx.x * BN;
  const int arow = lane & 15;
  const int kgrp = lane >> 4;
  const int strow = lane >> 2;
  const int stk = (lane & 3) * 8;
  f32x4 acc[FM][FN] = {};

  for (int k0 = 0; k0 < K; k0 += 32) {
    #pragma unroll
    for (int p = 0; p < 2; ++p) {
      const u16* Ap = p ? Al : Ah;
      #pragma unroll
      for (int i = 0; i < BM / 64; ++i) {
        int r0 = (wid + 4 * i) * 16;
        gload_lds16(Ap + (size_t)(bm + r0 + strow) * K + k0 + stk,
                    &As[p][r0 * 32]);
      }
      const u16* Bp = p ? Bl : Bh;
      #pragma unroll
      for (int i = 0; i < BN / 64; ++i) {
        int r0 = (wid + 4 * i) * 16;
        gload_lds16(Bp + (size_t)(bn + r0 + strow) * K + k0 + stk,
                    &Bs[p][r0 * 32]);
      }
    }
    __syncthreads();
    short8 ah[FM], al[FM], bh[FN], bl[FN];
    #pragma unroll
    for (int mi = 0; mi < FM; ++mi) {
      int off = (wr * WM + mi * 16 + arow) * 32 + kgrp * 8;
      ah[mi] = *(const short8*)&As[0][off];
      al[mi] = *(const short8*)&As[1][off];
    }
    #pragma unroll
    for (int ni = 0; ni < FN; ++ni) {
      int off = (wc * WN + ni * 16 + arow) * 32 + kgrp * 8;
      bh[ni] = *(const short8*)&Bs[0][off];
      bl[ni] = *(const short8*)&Bs[1][off];
    }
    #pragma unroll
    for (int mi = 0; mi < FM; ++mi)
      #pragma unroll
      for (int ni = 0; ni < FN; ++ni) {
        acc[mi][ni] = __builtin_amdgcn_mfma_f32_16x16x32_bf16(
            ah[mi], bh[ni], acc[mi][ni], 0, 0, 0);
        acc[mi][ni] = __builtin_amdgcn_mfma_f32_16x16x32_bf16(
            ah[mi], bl[ni], acc[mi][ni], 0, 0, 0);
        acc[mi][ni] = __builtin_amdgcn_mfma_f32_16x16x32_bf16(
            al[mi], bh[ni], acc[mi][ni], 0, 0, 0);
      }
    __syncthreads();
  }
  // epilogue; C/D layout: col = lane&15, row = (lane>>4)*4 + j
  #pragma unroll
  for (int mi = 0; mi < FM; ++mi)
    #pragma unroll
    for (int ni = 0; ni < FN; ++ni) {
      int col = bn + wc * WN + ni * 16 + (lane & 15);
      float bv = (EPI >= 1 && EPI <= 3) ? bias[col] : 0.f;
      #pragma unroll
      for (int j = 0; j < 4; ++j) {
        int row = bm + wr * WM + mi * 16 + (lane >> 4) * 4 + j;
        float v = acc[mi][ni][j] + bv;
        size_t o = (size_t)row * ldC + col;
        if (EPI == 2) {
          v = fmaxf(v, 0.f);
          u16 hh, ll;
          split2(v, hh, ll);
          Ch[o] = hh;
          Cl[o] = ll;
        } else if (EPI == 3) {
          Cf[o] = v + resid[o];
        } else if (EPI == 4) {
          int sec = col >> 10;           // 0=q,1=k,2=v
          int nh = (col >> 6) & 15;
          int d = col & 63;
          int bz = row >> 10;
          int t = row & (TSEQ - 1);
          int bh_ = bz * NHEAD + nh;
          u16 hh, ll;
          split2(v, hh, ll);
          if (sec == 0) {
            size_t o2 = ((size_t)bh_ * TSEQ + t) * 64 + d;
            Ch[o2] = hh; Cl[o2] = ll;
          } else if (sec == 1) {
            size_t o2 = ((size_t)bh_ * TSEQ + t) * 64 + d;
            Ch2[o2] = hh; Cl2[o2] = ll;
          } else {
            size_t o2 = ((size_t)bh_ * 64 + d) * TSEQ + t;
            Ch3[o2] = hh; Cl3[o2] = ll;
          }
        } else {
          Cf[o] = v;
        }
      }
    }
}

// ---------------------------------------------------------------------------
// MFMA flash attention. Q,K planes [bh][t][64]; V^T planes [bh][64][t].
// Block = 4 waves, 64 queries; wave owns 16 q-rows. Key tiles of 64.
// QK^T: 3-term split MFMA. P: single bf16 via per-wave swizzled LDS.
// PV: P*Vh + P*Vl. LDS tiles XOR-swizzled (granule 8 elem): content
// [row][8a+i] = src[row][8(a^(row&7))+i]; staged via pre-swizzled global src.
// ---------------------------------------------------------------------------
__global__ __launch_bounds__(256) void mattn_kernel(
    const u16* __restrict__ Qh, const u16* __restrict__ Ql,
    const u16* __restrict__ Kh, const u16* __restrict__ Kl,
    const u16* __restrict__ Vth, const u16* __restrict__ Vtl,
    u16* __restrict__ oh, u16* __restrict__ ol) {
  __shared__ u16 Ksh[2][64 * 64];   // [plane][key*64 + d']
  __shared__ u16 Vsh[2][64 * 64];   // [plane][d*64 + s']
  __shared__ u16 Psh[4][16 * 64];   // per-wave [q*64 + s']
  const int qb = blockIdx.x, h = blockIdx.y, b = blockIdx.z;
  const int tid = threadIdx.x, wid = tid >> 6, lane = tid & 63;
  const int g = lane >> 4;          // 0..3
  const int fr = lane & 15;         // 0..15
  const int bh_ = b * NHEAD + h;
  const size_t qkbase = (size_t)bh_ * TSEQ * 64;
  const size_t vbase  = (size_t)bh_ * 64 * TSEQ;
  // Q A-frags (row = fr, k = g*8 within 32-step)
  const int qrow = qb * 64 + wid * 16 + fr;
  short8 qfh[2], qfl[2];
  #pragma unroll
  for (int dstep = 0; dstep < 2; ++dstep) {
    size_t o = qkbase + (size_t)qrow * 64 + dstep * 32 + g * 8;
    qfh[dstep] = *(const short8*)&Qh[o];
    qfl[dstep] = *(const short8*)&Ql[o];
  }
  f32x4 oacc[4] = {};
  float mrow[4], lrow[4];
  #pragma unroll
  for (int j = 0; j < 4; ++j) { mrow[j] = -3e30f; lrow[j] = 0.f; }

  const int srow = lane >> 3;       // 0..7 staging row offset
  const int sgran = lane & 7;       // staging granule

  for (int kt = 0; kt <= qb; ++kt) {
    const int t0 = kt * 64;
    __syncthreads();   // all waves done reading previous K/V tile
    #pragma unroll
    for (int i = 0; i < 2; ++i) {
      int r = wid * 16 + i * 8 + srow;          // local row 0..63
      int cg = 8 * (sgran ^ (r & 7));           // pre-swizzled source granule
      int dst = (wid * 16 + i * 8) * 64;        // wave-uniform LDS base
      gload_lds16(&Kh[qkbase + (size_t)(t0 + r) * 64 + cg], &Ksh[0][dst]);
      gload_lds16(&Kl[qkbase + (size_t)(t0 + r) * 64 + cg], &Ksh[1][dst]);
      gload_lds16(&Vth[vbase + (size_t)r * TSEQ + t0 + cg], &Vsh[0][dst]);
      gload_lds16(&Vtl[vbase + (size_t)r * TSEQ + t0 + cg], &Vsh[1][dst]);
    }
    __syncthreads();
    // ---- S = Q K^T (4 key sub-tiles x 2 d-steps x 3-term split) ----
    f32x4 sacc[4] = {};
    #pragma unroll
    for (int ktile = 0; ktile < 4; ++ktile) {
      int key = ktile * 16 + fr;
      #pragma unroll
      for (int dstep = 0; dstep < 2; ++dstep) {
        int off = key * 64 + 8 * ((4 * dstep + g) ^ (key & 7));
        short8 kfh = *(const short8*)&Ksh[0][off];
        short8 kfl = *(const short8*)&Ksh[1][off];
        sacc[ktile] = __builtin_amdgcn_mfma_f32_16x16x32_bf16(
            qfh[dstep], kfh, sacc[ktile], 0, 0, 0);
        sacc[ktile] = __builtin_amdgcn_mfma_f32_16x16x32_bf16(
            qfh[dstep], kfl, sacc[ktile], 0, 0, 0);
        sacc[ktile] = __builtin_amdgcn_mfma_f32_16x16x32_bf16(
            qfl[dstep], kfh, sacc[ktile], 0, 0, 0);
      }
    }
    // ---- scale + causal mask + online softmax ----
    float p[4][4];     // [ktile][j]
    float mtile[4] = {-3e30f, -3e30f, -3e30f, -3e30f};
    #pragma unroll
    for (int ktile = 0; ktile < 4; ++ktile)
      #pragma unroll
      for (int j = 0; j < 4; ++j) {
        float s = sacc[ktile][j] * 0.125f;
        if (kt == qb) {
          int key = t0 + ktile * 16 + fr;
          int qg = qb * 64 + wid * 16 + g * 4 + j;
          if (key > qg) s = -3e30f;
        }
        p[ktile][j] = s;
        mtile[j] = fmaxf(mtile[j], s);
      }
    #pragma unroll
    for (int j = 0; j < 4; ++j) {
      float v = mtile[j];
      v = fmaxf(v, __shfl_xor(v, 1));
      v = fmaxf(v, __shfl_xor(v, 2));
      v = fmaxf(v, __shfl_xor(v, 4));
      v = fmaxf(v, __shfl_xor(v, 8));
      float mnew = fmaxf(mrow[j], v);
      float corr = __expf(mrow[j] - mnew);
      mrow[j] = mnew;
      float sum = 0.f;
      #pragma unroll
      for (int ktile = 0; ktile < 4; ++ktile) {
        float w = __expf(p[ktile][j] - mnew);
        p[ktile][j] = w;
        sum += w;
      }
      sum += __shfl_xor(sum, 1);
      sum += __shfl_xor(sum, 2);
      sum += __shfl_xor(sum, 4);
      sum += __shfl_xor(sum, 8);
      lrow[j] = lrow[j] * corr + sum;
      #pragma unroll
      for (int ni = 0; ni < 4; ++ni) oacc[ni][j] *= corr;
    }
    // ---- P -> per-wave swizzled LDS (bf16) ----
    #pragma unroll
    for (int ktile = 0; ktile < 4; ++ktile)
      #pragma unroll
      for (int j = 0; j < 4; ++j) {
        int q = g * 4 + j;
        int s = ktile * 16 + fr;
        Psh[wid][q * 64 + (s ^ (8 * (q & 7)))] = (u16)bf16rne(p[ktile][j]);
      }
    // ---- O += P @ V (A=P frag, B=Vt frag, 2-term: Vh+Vl) ----
    #pragma unroll
    for (int ss = 0; ss < 2; ++ss) {
      int aoff = fr * 64 + 8 * ((4 * ss + g) ^ (fr & 7));
      short8 pa = *(const short8*)&Psh[wid][aoff];
      #pragma unroll
      for (int ni = 0; ni < 4; ++ni) {
        int d = ni * 16 + fr;
        int boff = d * 64 + 8 * ((4 * ss + g) ^ (d & 7));
        short8 vfh = *(const short8*)&Vsh[0][boff];
        short8 vfl = *(const short8*)&Vsh[1][boff];
        oacc[ni] = __builtin_amdgcn_mfma_f32_16x16x32_bf16(pa, vfh, oacc[ni], 0, 0, 0);
        oacc[ni] = __builtin_amdgcn_mfma_f32_16x16x32_bf16(pa, vfl, oacc[ni], 0, 0, 0);
      }
    }
  }
  // ---- normalize + write att planes (concat-head [b*T+t][C]) ----
  float inv[4];
  #pragma unroll
  for (int j = 0; j < 4; ++j) inv[j] = 1.f / lrow[j];
  #pragma unroll
  for (int ni = 0; ni < 4; ++ni) {
    int d = ni * 16 + fr;
    #pragma unroll
    for (int j = 0; j < 4; ++j) {
      int q = qb * 64 + wid * 16 + g * 4 + j;
      float v = oacc[ni][j] * inv[j];
      u16 hh, ll;
      split2(v, hh, ll);
      size_t o = (size_t)(b * TSEQ + q) * CDIM + h * HSZ + d;
      oh[o] = hh;
      ol[o] = ll;
    }
  }
}

// ---------------------------------------------------------------------------
extern "C" void kernel_launch(void* const* d_in, const int* in_sizes, int n_in,
                              void* d_out, int out_size, void* d_ws,
                              size_t ws_size, hipStream_t stream) {
  (void)in_sizes; (void)n_in; (void)out_size; (void)ws_size;
  const int*   idx     = (const int*)  d_in[0];
  const float* tok_emb = (const float*)d_in[1];
  const float* pos_emb = (const float*)d_in[2];
  const float* Wq      = (const float*)d_in[3];
  const float* Wk      = (const float*)d_in[4];
  const float* Wv      = (const float*)d_in[5];
  const float* Wo      = (const float*)d_in[6];
  const float* bo      = (const float*)d_in[7];
  const float* ln1_s   = (const float*)d_in[8];
  const float* ln1_b   = (const float*)d_in[9];
  const float* ln2_s   = (const float*)d_in[10];
  const float* ln2_b   = (const float*)d_in[11];
  const float* W1      = (const float*)d_in[12];
  const float* b1      = (const float*)d_in[13];
  const float* W2      = (const float*)d_in[14];
  const float* b2      = (const float*)d_in[15];
  const float* lnf_s   = (const float*)d_in[16];
  const float* lnf_b   = (const float*)d_in[17];
  const float* W_lm    = (const float*)d_in[18];
  const float* b_lm    = (const float*)d_in[19];
  float* out = (float*)d_out;

  // workspace map (bytes), total 84,934,656
  char* wsb = (char*)d_ws;
  float* x    = (float*)wsb;                    //  8,388,608 fp32 residual
  u16* h_h    = (u16*)(wsb + 8388608);          //  4,194,304 LN out hi
  u16* h_l    = (u16*)(wsb + 12582912);         //  4,194,304 LN out lo
  u16* att_h  = (u16*)(wsb + 16777216);         //  4,194,304
  u16* att_l  = (u16*)(wsb + 20971520);         //  4,194,304
  char* big   = wsb + 25165824;                 // 33,554,432 shared region
  u16* q_h    = (u16*)(big);                    //  4 MB each plane:
  u16* q_l    = (u16*)(big + 4194304);
  u16* k_h    = (u16*)(big + 8388608);
  u16* k_l    = (u16*)(big + 12582912);
  u16* vt_h   = (u16*)(big + 16777216);
  u16* vt_l   = (u16*)(big + 20971520);
  u16* mid_h  = (u16*)big;                      // 16 MB (reuses qkv planes)
  u16* mid_l  = (u16*)(big + 16777216);         // 16 MB
  u16* wb_h   = (u16*)(wsb + 58720256);         // 13,107,200 weight plane hi
  u16* wb_l   = (u16*)(wsb + 71827456);         // 13,107,200 weight plane lo

  embed_kernel<<<NROWS, 256, 0, stream>>>(idx, tok_emb, pos_emb, x);

  for (int l = 0; l < NLAYER; ++l) {
    ln_kernel<<<NROWS, 256, 0, stream>>>(x, h_h, h_l, ln1_s + l * CDIM,
                                         ln1_b + l * CDIM);
    const size_t lq = (size_t)l * NHEAD * CDIM * HSZ;
    wcvt_kernel<<<dim3(2, 32, 16), 256, 0, stream>>>(
        Wq + lq, HSZ, 0, wb_h, wb_l, CDIM, (size_t)CDIM * HSZ, (size_t)HSZ * CDIM);
    wcvt_kernel<<<dim3(2, 32, 16), 256, 0, stream>>>(
        Wk + lq, HSZ, 0, wb_h + 1048576, wb_l + 1048576, CDIM,
        (size_t)CDIM * HSZ, (size_t)HSZ * CDIM);
    wcvt_kernel<<<dim3(2, 32, 16), 256, 0, stream>>>(
        Wv + lq, HSZ, 0, wb_h + 2097152, wb_l + 2097152, CDIM,
        (size_t)CDIM * HSZ, (size_t)HSZ * CDIM);
    // fused QKV GEMM -> split planes (Q,K per-head; V transposed)
    mgemm<128, 128, 64, 64, 4><<<dim3(3072 / 128, NROWS / 128), 256, 0, stream>>>(
        h_h, h_l, wb_h, wb_l, nullptr, q_h, q_l, k_h, k_l, vt_h, vt_l,
        nullptr, nullptr, NROWS, 3072, CDIM, 3072);
    mattn_kernel<<<dim3(TSEQ / 64, NHEAD, BB), 256, 0, stream>>>(
        q_h, q_l, k_h, k_l, vt_h, vt_l, att_h, att_l);
    // Wo: x += att @ Wo + bo
    wcvt_kernel<<<dim3(32, 32, 1), 256, 0, stream>>>(
        Wo + (size_t)l * CDIM * CDIM, CDIM, 0, wb_h, wb_l, CDIM, 0, 0);
    mgemm<64, 128, 32, 64, 3><<<dim3(CDIM / 128, NROWS / 64), 256, 0, stream>>>(
        att_h, att_l, wb_h, wb_l, x, nullptr, nullptr, nullptr, nullptr,
        nullptr, nullptr, bo + l * CDIM, x, NROWS, CDIM, CDIM, CDIM);
    ln_kernel<<<NROWS, 256, 0, stream>>>(x, h_h, h_l, ln2_s + l * CDIM,
                                         ln2_b + l * CDIM);
    // MLP1: mid = relu(h @ W1 + b1) -> planes
    wcvt_kernel<<<dim3(128, 32, 1), 256, 0, stream>>>(
        W1 + (size_t)l * CDIM * 4096, 4096, 0, wb_h, wb_l, CDIM, 0, 0);
    mgemm<128, 128, 64, 64, 2><<<dim3(4096 / 128, NROWS / 128), 256, 0, stream>>>(
        h_h, h_l, wb_h, wb_l, nullptr, mid_h, mid_l, nullptr, nullptr,
        nullptr, nullptr, b1 + l * 4096, nullptr, NROWS, 4096, CDIM, 4096);
    // MLP2: x += mid @ W2 + b2
    wcvt_kernel<<<dim3(32, 128, 1), 256, 0, stream>>>(
        W2 + (size_t)l * 4096 * CDIM, CDIM, 0, wb_h, wb_l, 4096, 0, 0);
    mgemm<64, 128, 32, 64, 3><<<dim3(CDIM / 128, NROWS / 64), 256, 0, stream>>>(
        mid_h, mid_l, wb_h, wb_l, x, nullptr, nullptr, nullptr, nullptr,
        nullptr, nullptr, b2 + l * CDIM, x, NROWS, CDIM, 4096, CDIM);
  }

  ln_kernel<<<NROWS, 256, 0, stream>>>(x, h_h, h_l, lnf_s, lnf_b);
  // LM head in 5 chunks of N=6400
  for (int c = 0; c < 5; ++c) {
    int col0 = c * 6400;
    wcvt_kernel<<<dim3(200, 32, 1), 256, 0, stream>>>(
        W_lm, VDIM, col0, wb_h, wb_l, CDIM, 0, 0);
    mgemm<128, 128, 64, 64, 1><<<dim3(50, NROWS / 128), 256, 0, stream>>>(
        h_h, h_l, wb_h, wb_l, out + col0, nullptr, nullptr, nullptr, nullptr,
        nullptr, nullptr, b_lm + col0, nullptr, NROWS, 6400, CDIM, VDIM);
  }
}